// Round 2
// baseline (6413.573 us; speedup 1.0000x reference)
//
#include <hip/hip_runtime.h>
#include <cstddef>

#define N_NODES 100000
#define N_EDGES 1600000
#define F_IN 500
#define HID 128
#define N_CLASSES 16

// ---------------------------------------------------------------------------
// degree histogram: deg[dst] += 1 over 1.6M edges (self-loop +1 added in dinv)
// ---------------------------------------------------------------------------
__global__ __launch_bounds__(256) void count_deg_k(const int* __restrict__ dst,
                                                   float* __restrict__ deg) {
  int i = blockIdx.x * 256 + threadIdx.x;
  if (i < N_EDGES) atomicAdd(&deg[dst[i]], 1.0f);
}

__global__ __launch_bounds__(256) void dinv_k(float* __restrict__ deg) {
  int i = blockIdx.x * 256 + threadIdx.x;
  if (i < N_NODES) deg[i] = 1.0f / sqrtf(deg[i] + 1.0f);  // +1 = self-loop
}

// ---------------------------------------------------------------------------
// f32 tile GEMM, N fixed at 128. C[M,128] = A[M,K] * W[K,128]
// 64-row tile, 256 threads, each thread 4x8 outputs.
// ---------------------------------------------------------------------------
__global__ __launch_bounds__(256) void gemm_n128(const float* __restrict__ A,
                                                 const float* __restrict__ W,
                                                 float* __restrict__ C,
                                                 int M, int K, int lda) {
  __shared__ float xs[64][17];   // +1 pad: avoids bank conflict on column reads
  __shared__ float ws[16][128];
  const int tid = threadIdx.x;
  const int r0 = blockIdx.x * 64;
  const int tx = tid & 15;   // col group: cols tx*8 .. tx*8+7
  const int ty = tid >> 4;   // row group: rows ty*4 .. ty*4+3

  float acc[4][8];
#pragma unroll
  for (int i = 0; i < 4; ++i)
#pragma unroll
    for (int j = 0; j < 8; ++j) acc[i][j] = 0.0f;

  for (int k0 = 0; k0 < K; k0 += 16) {
    // stage A tile 64x16 (zero-fill K tail / row tail)
#pragma unroll
    for (int l = 0; l < 4; ++l) {
      int idx = tid + l * 256;
      int r = idx >> 4, kk = idx & 15;
      int gr = r0 + r, gk = k0 + kk;
      xs[r][kk] = (gr < M && gk < K) ? A[(size_t)gr * lda + gk] : 0.0f;
    }
    // stage W tile 16x128
#pragma unroll
    for (int l = 0; l < 8; ++l) {
      int idx = tid + l * 256;
      int kk = idx >> 7, c = idx & 127;
      int gk = k0 + kk;
      ws[kk][c] = (gk < K) ? W[(size_t)gk * 128 + c] : 0.0f;
    }
    __syncthreads();
#pragma unroll
    for (int kk = 0; kk < 16; ++kk) {
      const float aa0 = xs[ty * 4 + 0][kk];
      const float aa1 = xs[ty * 4 + 1][kk];
      const float aa2 = xs[ty * 4 + 2][kk];
      const float aa3 = xs[ty * 4 + 3][kk];
      const float4 b0 = *(const float4*)&ws[kk][tx * 8];
      const float4 b1 = *(const float4*)&ws[kk][tx * 8 + 4];
      const float aa[4] = {aa0, aa1, aa2, aa3};
      const float bb[8] = {b0.x, b0.y, b0.z, b0.w, b1.x, b1.y, b1.z, b1.w};
#pragma unroll
      for (int i = 0; i < 4; ++i)
#pragma unroll
        for (int j = 0; j < 8; ++j) acc[i][j] += aa[i] * bb[j];
    }
    __syncthreads();
  }
#pragma unroll
  for (int i = 0; i < 4; ++i) {
    int row = r0 + ty * 4 + i;
    if (row < M) {
      float4 v0 = make_float4(acc[i][0], acc[i][1], acc[i][2], acc[i][3]);
      float4 v1 = make_float4(acc[i][4], acc[i][5], acc[i][6], acc[i][7]);
      *(float4*)&C[(size_t)row * 128 + tx * 8] = v0;
      *(float4*)&C[(size_t)row * 128 + tx * 8 + 4] = v1;
    }
  }
}

// ---------------------------------------------------------------------------
// out[n][:] = h[n][:] * dinv[n]^2   (self-loop term; also initializes buffer)
// one float4 per thread
// ---------------------------------------------------------------------------
__global__ __launch_bounds__(256) void self_init_k(const float* __restrict__ h,
                                                   const float* __restrict__ dinv,
                                                   float* __restrict__ out) {
  size_t i = (size_t)blockIdx.x * 256 + threadIdx.x;   // float4 index
  if (i < (size_t)N_NODES * 32) {
    int n = (int)(i >> 5);
    float di = dinv[n];
    float s = di * di;
    float4 v = ((const float4*)h)[i];
    v.x *= s; v.y *= s; v.z *= s; v.w *= s;
    ((float4*)out)[i] = v;
  }
}

// ---------------------------------------------------------------------------
// edge scatter: out[dst][:] += h[src][:] * dinv[src]*dinv[dst]
// 32 lanes per edge (float4 each), 8 edges per 256-thread block
// ---------------------------------------------------------------------------
__global__ __launch_bounds__(256) void scatter_k(const float* __restrict__ h,
                                                 const int* __restrict__ src,
                                                 const int* __restrict__ dst,
                                                 const float* __restrict__ dinv,
                                                 float* __restrict__ out) {
  int e = blockIdx.x * 8 + (threadIdx.x >> 5);
  if (e >= N_EDGES) return;
  int lane = threadIdx.x & 31;
  int s = src[e];
  int d = dst[e];
  float norm = dinv[s] * dinv[d];
  float4 v = ((const float4*)(h + (size_t)s * 128))[lane];
  float* o = out + (size_t)d * 128 + lane * 4;
  atomicAdd(o + 0, v.x * norm);
  atomicAdd(o + 1, v.y * norm);
  atomicAdd(o + 2, v.z * norm);
  atomicAdd(o + 3, v.w * norm);
}

// ---------------------------------------------------------------------------
// a[n][f] = relu(a[n][f] + b[f])
// ---------------------------------------------------------------------------
__global__ __launch_bounds__(256) void relu_bias_k(float* __restrict__ a,
                                                   const float* __restrict__ b) {
  size_t i = (size_t)blockIdx.x * 256 + threadIdx.x;
  if (i < (size_t)N_NODES * 128) a[i] = fmaxf(a[i] + b[i & 127], 0.0f);
}

// ---------------------------------------------------------------------------
// logits = h @ Wfc + bfc ; softmax over 16 classes. 16 rows per block.
// thread (r,c): r = tid>>4 row-in-block, c = tid&15 class.
// ---------------------------------------------------------------------------
__global__ __launch_bounds__(256) void fc_softmax_k(const float* __restrict__ h,
                                                    const float* __restrict__ Wfc,
                                                    const float* __restrict__ bfc,
                                                    float* __restrict__ out) {
  __shared__ float wsh[128 * 16];
  __shared__ float hsh[16][129];
  const int tid = threadIdx.x;
  const int r0 = blockIdx.x * 16;   // N_NODES % 16 == 0, no guards needed
#pragma unroll
  for (int l = 0; l < 8; ++l) wsh[tid + l * 256] = Wfc[tid + l * 256];
#pragma unroll
  for (int l = 0; l < 8; ++l) {
    int idx = tid + l * 256;
    int r = idx >> 7, k = idx & 127;
    hsh[r][k] = h[(size_t)(r0 + r) * 128 + k];
  }
  __syncthreads();
  const int r = tid >> 4;
  const int c = tid & 15;
  float acc = bfc[c];
#pragma unroll
  for (int k = 0; k < 128; ++k) acc += hsh[r][k] * wsh[k * 16 + c];
  // softmax across the 16 lanes of this row (contiguous lanes within a wave)
  float m = acc;
#pragma unroll
  for (int off = 1; off < 16; off <<= 1) m = fmaxf(m, __shfl_xor(m, off, 16));
  float ex = expf(acc - m);
  float s = ex;
#pragma unroll
  for (int off = 1; off < 16; off <<= 1) s += __shfl_xor(s, off, 16);
  out[(size_t)(r0 + r) * 16 + c] = ex / s;
}

// ---------------------------------------------------------------------------
extern "C" void kernel_launch(void* const* d_in, const int* in_sizes, int n_in,
                              void* d_out, int out_size, void* d_ws, size_t ws_size,
                              hipStream_t stream) {
  const float* x      = (const float*)d_in[0];
  const int*   ei     = (const int*)d_in[1];   // harness delivers integer inputs as int32
  const float* W1     = (const float*)d_in[2];
  const float* b1     = (const float*)d_in[3];
  const float* W2     = (const float*)d_in[4];
  const float* b2     = (const float*)d_in[5];
  const float* Wfc    = (const float*)d_in[6];
  const float* bfc    = (const float*)d_in[7];
  float* out          = (float*)d_out;

  const int* srcIdx = ei;             // row 0
  const int* dstIdx = ei + N_EDGES;   // row 1

  float* ws   = (float*)d_ws;
  float* dinv = ws;                                   // N_NODES floats (deg -> dinv in place)
  float* bufA = ws + (1 << 17);                       // 12.8M floats
  float* bufB = bufA + (size_t)N_NODES * HID;         // 12.8M floats

  const size_t NF4 = (size_t)N_NODES * 32;            // node-feature float4 count

  // degrees -> dinv
  hipMemsetAsync(dinv, 0, N_NODES * sizeof(float), stream);
  count_deg_k<<<(N_EDGES + 255) / 256, 256, 0, stream>>>(dstIdx, dinv);
  dinv_k<<<(N_NODES + 255) / 256, 256, 0, stream>>>(dinv);

  // layer 1: h1 = x @ W1 ; agg ; relu(+b1)
  gemm_n128<<<(N_NODES + 63) / 64, 256, 0, stream>>>(x, W1, bufA, N_NODES, F_IN, F_IN);
  self_init_k<<<(int)(NF4 / 256), 256, 0, stream>>>(bufA, dinv, bufB);
  scatter_k<<<(N_EDGES + 7) / 8, 256, 0, stream>>>(bufA, srcIdx, dstIdx, dinv, bufB);
  relu_bias_k<<<(int)((size_t)N_NODES * 128 / 256), 256, 0, stream>>>(bufB, b1);

  // layer 2: h2 = relu1 @ W2 ; agg ; relu(+b2)
  gemm_n128<<<(N_NODES + 63) / 64, 256, 0, stream>>>(bufB, W2, bufA, N_NODES, HID, HID);
  self_init_k<<<(int)(NF4 / 256), 256, 0, stream>>>(bufA, dinv, bufB);
  scatter_k<<<(N_EDGES + 7) / 8, 256, 0, stream>>>(bufA, srcIdx, dstIdx, dinv, bufB);
  relu_bias_k<<<(int)((size_t)N_NODES * 128 / 256), 256, 0, stream>>>(bufB, b2);

  // fc + softmax
  fc_softmax_k<<<N_NODES / 16, 256, 0, stream>>>(bufB, Wfc, bfc, out);
}

// Round 7
// 1354.583 us; speedup vs baseline: 4.7347x; 4.7347x over previous
//
#include <hip/hip_runtime.h>
#include <cstddef>

#define N_NODES 100000
#define N_EDGES 1600000
#define F_IN 500
#define HID 128
#define N_CLASSES 16
#define SCAN_NB ((N_NODES + 511) / 512)   // 196

// ---------------------------------------------------------------------------
// degree histogram (int): deg[dst] += 1 over edges (self-loop +1 added later)
// ---------------------------------------------------------------------------
__global__ __launch_bounds__(256) void count_deg_k(const int* __restrict__ dst,
                                                   int* __restrict__ deg) {
  int i = blockIdx.x * 256 + threadIdx.x;
  if (i < N_EDGES) atomicAdd(&deg[dst[i]], 1);
}

__global__ __launch_bounds__(256) void dinv_k(const int* __restrict__ deg,
                                              float* __restrict__ dinv) {
  int i = blockIdx.x * 256 + threadIdx.x;
  if (i < N_NODES) dinv[i] = rsqrtf((float)deg[i] + 1.0f);  // +1 = self-loop
}

// ---------------------------------------------------------------------------
// exclusive scan of deg -> rowptr (3 phases)
// ---------------------------------------------------------------------------
__global__ __launch_bounds__(512) void scan1_k(const int* __restrict__ deg,
                                               int* __restrict__ part,
                                               int* __restrict__ bsum) {
  __shared__ int tmp[512];
  const int tid = threadIdx.x;
  const int idx = blockIdx.x * 512 + tid;
  tmp[tid] = (idx < N_NODES) ? deg[idx] : 0;
  __syncthreads();
#pragma unroll
  for (int off = 1; off < 512; off <<= 1) {
    int t = (tid >= off) ? tmp[tid - off] : 0;
    __syncthreads();
    tmp[tid] += t;
    __syncthreads();
  }
  if (idx < N_NODES) part[idx] = tmp[tid];          // inclusive within block
  if (tid == 511) bsum[blockIdx.x] = tmp[511];
}

__global__ __launch_bounds__(256) void scan2_k(int* __restrict__ bsum) {
  __shared__ int tmp[256];
  const int tid = threadIdx.x;
  tmp[tid] = (tid < SCAN_NB) ? bsum[tid] : 0;
  __syncthreads();
#pragma unroll
  for (int off = 1; off < 256; off <<= 1) {
    int t = (tid >= off) ? tmp[tid - off] : 0;
    __syncthreads();
    tmp[tid] += t;
    __syncthreads();
  }
  if (tid < SCAN_NB) bsum[tid] = (tid == 0) ? 0 : tmp[tid - 1];  // exclusive block offset
}

__global__ __launch_bounds__(512) void scan3_k(const int* __restrict__ deg,
                                               const int* __restrict__ part,
                                               const int* __restrict__ bsum,
                                               int* __restrict__ rowptr,
                                               int* __restrict__ wofs) {
  const int idx = blockIdx.x * 512 + threadIdx.x;
  if (idx < N_NODES) {
    int ex = part[idx] - deg[idx] + bsum[blockIdx.x];
    rowptr[idx] = ex;
    wofs[idx] = ex;
  }
}

// ---------------------------------------------------------------------------
// bucket edges into CSR order (dst-sorted src list)
// ---------------------------------------------------------------------------
__global__ __launch_bounds__(256) void fill_k(const int* __restrict__ src,
                                              const int* __restrict__ dst,
                                              int* __restrict__ wofs,
                                              int* __restrict__ csr_src) {
  int e = blockIdx.x * 256 + threadIdx.x;
  if (e < N_EDGES) {
    int d = dst[e];
    int pos = atomicAdd(&wofs[d], 1);
    csr_src[pos] = src[e];
  }
}

// ---------------------------------------------------------------------------
// CSR aggregation, fused self-loop + bias + relu:
// out[d][:] = relu( dinv_d*( dinv_d*h[d][:] + sum_j dinv_sj*h[src_j][:] ) + b[:] )
// 32 lanes per node (one float4 each), 8 nodes per 256-thread block.
// ---------------------------------------------------------------------------
__global__ __launch_bounds__(256) void agg_k(const float* __restrict__ h,
                                             const int* __restrict__ rowptr,
                                             const int* __restrict__ deg,
                                             const int* __restrict__ csr_src,
                                             const float* __restrict__ dinv,
                                             const float* __restrict__ bias,
                                             float* __restrict__ out) {
  const int node = blockIdx.x * 8 + (threadIdx.x >> 5);
  if (node >= N_NODES) return;
  const int lane = threadIdx.x & 31;
  const float4* h4 = (const float4*)h;

  const float dd = dinv[node];
  float4 a = h4[(size_t)node * 32 + lane];
  float4 acc = make_float4(a.x * dd, a.y * dd, a.z * dd, a.w * dd);

  const int beg = rowptr[node];
  const int n = deg[node];
  for (int j = 0; j < n; ++j) {
    const int sidx = csr_src[beg + j];
    const float w = dinv[sidx];
    float4 v = h4[(size_t)sidx * 32 + lane];
    acc.x += w * v.x;
    acc.y += w * v.y;
    acc.z += w * v.z;
    acc.w += w * v.w;
  }
  const float4 b4 = ((const float4*)bias)[lane];
  acc.x = fmaxf(acc.x * dd + b4.x, 0.0f);
  acc.y = fmaxf(acc.y * dd + b4.y, 0.0f);
  acc.z = fmaxf(acc.z * dd + b4.z, 0.0f);
  acc.w = fmaxf(acc.w * dd + b4.w, 0.0f);
  ((float4*)out)[(size_t)node * 32 + lane] = acc;
}

// ---------------------------------------------------------------------------
// f32 tile GEMM, N fixed at 128. C[M,128] = A[M,K] * W[K,128]
// ---------------------------------------------------------------------------
__global__ __launch_bounds__(256) void gemm_n128(const float* __restrict__ A,
                                                 const float* __restrict__ W,
                                                 float* __restrict__ C,
                                                 int M, int K, int lda) {
  __shared__ float xs[64][17];
  __shared__ float ws[16][128];
  const int tid = threadIdx.x;
  const int r0 = blockIdx.x * 64;
  const int tx = tid & 15;
  const int ty = tid >> 4;

  float acc[4][8];
#pragma unroll
  for (int i = 0; i < 4; ++i)
#pragma unroll
    for (int j = 0; j < 8; ++j) acc[i][j] = 0.0f;

  for (int k0 = 0; k0 < K; k0 += 16) {
#pragma unroll
    for (int l = 0; l < 4; ++l) {
      int idx = tid + l * 256;
      int r = idx >> 4, kk = idx & 15;
      int gr = r0 + r, gk = k0 + kk;
      xs[r][kk] = (gr < M && gk < K) ? A[(size_t)gr * lda + gk] : 0.0f;
    }
#pragma unroll
    for (int l = 0; l < 8; ++l) {
      int idx = tid + l * 256;
      int kk = idx >> 7, c = idx & 127;
      int gk = k0 + kk;
      ws[kk][c] = (gk < K) ? W[(size_t)gk * 128 + c] : 0.0f;
    }
    __syncthreads();
#pragma unroll
    for (int kk = 0; kk < 16; ++kk) {
      const float aa0 = xs[ty * 4 + 0][kk];
      const float aa1 = xs[ty * 4 + 1][kk];
      const float aa2 = xs[ty * 4 + 2][kk];
      const float aa3 = xs[ty * 4 + 3][kk];
      const float4 b0 = *(const float4*)&ws[kk][tx * 8];
      const float4 b1 = *(const float4*)&ws[kk][tx * 8 + 4];
      const float aa[4] = {aa0, aa1, aa2, aa3};
      const float bb[8] = {b0.x, b0.y, b0.z, b0.w, b1.x, b1.y, b1.z, b1.w};
#pragma unroll
      for (int i = 0; i < 4; ++i)
#pragma unroll
        for (int j = 0; j < 8; ++j) acc[i][j] += aa[i] * bb[j];
    }
    __syncthreads();
  }
#pragma unroll
  for (int i = 0; i < 4; ++i) {
    int row = r0 + ty * 4 + i;
    if (row < M) {
      float4 v0 = make_float4(acc[i][0], acc[i][1], acc[i][2], acc[i][3]);
      float4 v1 = make_float4(acc[i][4], acc[i][5], acc[i][6], acc[i][7]);
      *(float4*)&C[(size_t)row * 128 + tx * 8] = v0;
      *(float4*)&C[(size_t)row * 128 + tx * 8 + 4] = v1;
    }
  }
}

// ---------------------------------------------------------------------------
// logits = h @ Wfc + bfc ; softmax over 16 classes. 16 rows per block.
// ---------------------------------------------------------------------------
__global__ __launch_bounds__(256) void fc_softmax_k(const float* __restrict__ h,
                                                    const float* __restrict__ Wfc,
                                                    const float* __restrict__ bfc,
                                                    float* __restrict__ out) {
  __shared__ float wsh[128 * 16];
  __shared__ float hsh[16][129];
  const int tid = threadIdx.x;
  const int r0 = blockIdx.x * 16;
#pragma unroll
  for (int l = 0; l < 8; ++l) wsh[tid + l * 256] = Wfc[tid + l * 256];
#pragma unroll
  for (int l = 0; l < 8; ++l) {
    int idx = tid + l * 256;
    int r = idx >> 7, k = idx & 127;
    hsh[r][k] = h[(size_t)(r0 + r) * 128 + k];
  }
  __syncthreads();
  const int r = tid >> 4;
  const int c = tid & 15;
  float acc = bfc[c];
#pragma unroll
  for (int k = 0; k < 128; ++k) acc += hsh[r][k] * wsh[k * 16 + c];
  float m = acc;
#pragma unroll
  for (int off = 1; off < 16; off <<= 1) m = fmaxf(m, __shfl_xor(m, off, 16));
  float ex = expf(acc - m);
  float s = ex;
#pragma unroll
  for (int off = 1; off < 16; off <<= 1) s += __shfl_xor(s, off, 16);
  out[(size_t)(r0 + r) * 16 + c] = ex / s;
}

// ---------------------------------------------------------------------------
extern "C" void kernel_launch(void* const* d_in, const int* in_sizes, int n_in,
                              void* d_out, int out_size, void* d_ws, size_t ws_size,
                              hipStream_t stream) {
  const float* x   = (const float*)d_in[0];
  const int*   ei  = (const int*)d_in[1];   // int32 [2, N_EDGES]
  const float* W1  = (const float*)d_in[2];
  const float* b1  = (const float*)d_in[3];
  const float* W2  = (const float*)d_in[4];
  const float* b2  = (const float*)d_in[5];
  const float* Wfc = (const float*)d_in[6];
  const float* bfc = (const float*)d_in[7];
  float* out       = (float*)d_out;

  const int* srcIdx = ei;
  const int* dstIdx = ei + N_EDGES;

  // workspace layout (4-byte units) — permanent arrays (~110.5 MB total):
  //   rowptr[128K] | deg[128K] | dinv[128K] | csr_src[E] | bufA[12.8M] | bufB[12.8M]
  // transient scan arrays (part/wofs/bsum) alias into bufB: every use completes
  // (stream-ordered) before agg_k first writes bufB.
  const size_t ws_need =
      (3 * 131072ull + N_EDGES + 2ull * N_NODES * HID) * sizeof(float);
  if (ws_size < ws_need) {
    // Workspace too small for the CSR layout: fail validation CLEANLY
    // (absmax ~O(1)) instead of overrunning d_ws and killing the container.
    hipMemsetAsync(d_out, 0, (size_t)out_size * sizeof(float), stream);
    return;
  }

  int*   wsI     = (int*)d_ws;
  int*   rowptr  = wsI;
  int*   deg     = wsI + 1 * 131072;
  float* dinv    = (float*)(wsI + 2 * 131072);
  int*   csr_src = wsI + 3 * 131072;
  float* bufA    = (float*)(wsI + 3 * 131072 + N_EDGES);
  float* bufB    = bufA + (size_t)N_NODES * HID;
  int*   part    = (int*)bufB;
  int*   wofs    = (int*)bufB + 131072;
  int*   bsum    = (int*)bufB + 2 * 131072;

  // ---- CSR build ----
  hipMemsetAsync(deg, 0, N_NODES * sizeof(int), stream);
  count_deg_k<<<(N_EDGES + 255) / 256, 256, 0, stream>>>(dstIdx, deg);
  dinv_k<<<(N_NODES + 255) / 256, 256, 0, stream>>>(deg, dinv);
  scan1_k<<<SCAN_NB, 512, 0, stream>>>(deg, part, bsum);
  scan2_k<<<1, 256, 0, stream>>>(bsum);
  scan3_k<<<SCAN_NB, 512, 0, stream>>>(deg, part, bsum, rowptr, wofs);
  fill_k<<<(N_EDGES + 255) / 256, 256, 0, stream>>>(srcIdx, dstIdx, wofs, csr_src);

  // ---- layer 1 ----
  gemm_n128<<<(N_NODES + 63) / 64, 256, 0, stream>>>(x, W1, bufA, N_NODES, F_IN, F_IN);
  agg_k<<<(N_NODES + 7) / 8, 256, 0, stream>>>(bufA, rowptr, deg, csr_src,
                                               dinv, b1, bufB);

  // ---- layer 2 ----
  gemm_n128<<<(N_NODES + 63) / 64, 256, 0, stream>>>(bufB, W2, bufA, N_NODES, HID, HID);
  agg_k<<<(N_NODES + 7) / 8, 256, 0, stream>>>(bufA, rowptr, deg, csr_src,
                                               dinv, b2, bufB);

  // ---- fc + softmax ----
  fc_softmax_k<<<N_NODES / 16, 256, 0, stream>>>(bufB, Wfc, bfc, out);
}